// Round 9
// baseline (280.459 us; speedup 1.0000x reference)
//
#include <hip/hip_runtime.h>
#include <hip/hip_fp16.h>
#include <math.h>

#define NNODES 100000
#define NEG_SLOPE 0.2f
#define FIN 500
#define KP 512     // padded K
#define HID 128    // heads*hidden
#define NH 4

typedef __attribute__((ext_vector_type(8))) _Float16 half8v;
typedef __attribute__((ext_vector_type(4))) float f32x4;

__device__ __forceinline__ float lrelu(float x) { return x > 0.f ? x : NEG_SLOPE * x; }

__device__ __forceinline__ float sel4(float a0, float a1, float a2, float a3, int h) {
  float r = a0;
  r = (h == 1) ? a1 : r;
  r = (h == 2) ? a2 : r;
  r = (h == 3) ? a3 : r;
  return r;
}

// ---------------- W1 -> transposed fp16 [128][512] (zero-padded K) ----------------
__global__ __launch_bounds__(256) void convert_w1_kernel(const float* __restrict__ W1,
                                                         _Float16* __restrict__ BT) {
  int idx = blockIdx.x * 256 + threadIdx.x;  // 65536
  int n = idx >> 9, k = idx & 511;
  float v = (k < FIN) ? W1[k * HID + n] : 0.f;
  BT[n * KP + k] = (_Float16)v;
}

// ---------------- GEMM1: barrier-free fp16 MFMA, A global->reg, B from L1/L2 ----------------
// 4 independent waves per block; wave tile 32 rows x 128 cols; even/odd reg double-buffer.
__global__ __launch_bounds__(256, 2) void gemm1_mfma_kernel(const float* __restrict__ A,
                                                            const _Float16* __restrict__ BT,
                                                            const float* __restrict__ al,
                                                            const float* __restrict__ ar,
                                                            __half* __restrict__ z1h,
                                                            float* __restrict__ el,
                                                            float* __restrict__ er) {
  const int t = threadIdx.x;
  const int w = t >> 6, lane = t & 63;
  const int fr = lane & 15, ko = lane >> 4;
  const int bm = blockIdx.x * 128 + w * 32;   // wave's 32-row base

  const int r0 = min(bm + fr, NNODES - 1);
  const int r1 = min(bm + 16 + fr, NNODES - 1);
  const float* pA0 = A + (size_t)r0 * FIN + ko * 8;
  const float* pA1 = A + (size_t)r1 * FIN + ko * 8;
  const _Float16* pB0 = BT + (size_t)(0 * 16 + fr) * KP + ko * 8;
  const _Float16* pB1 = BT + (size_t)(1 * 16 + fr) * KP + ko * 8;
  const _Float16* pB2 = BT + (size_t)(2 * 16 + fr) * KP + ko * 8;
  const _Float16* pB3 = BT + (size_t)(3 * 16 + fr) * KP + ko * 8;
  const _Float16* pB4 = BT + (size_t)(4 * 16 + fr) * KP + ko * 8;
  const _Float16* pB5 = BT + (size_t)(5 * 16 + fr) * KP + ko * 8;
  const _Float16* pB6 = BT + (size_t)(6 * 16 + fr) * KP + ko * 8;
  const _Float16* pB7 = BT + (size_t)(7 * 16 + fr) * KP + ko * 8;

  f32x4 acc[2][8];
#pragma unroll
  for (int i = 0; i < 2; i++)
#pragma unroll
    for (int j = 0; j < 8; j++) acc[i][j] = (f32x4){0.f, 0.f, 0.f, 0.f};

  // even/odd register sets (named, statically indexed)
  f32x4 e0a, e0b, e1a, e1b, o0a, o0b, o1a, o1b;
  half8v be0, be1, be2, be3, be4, be5, be6, be7;
  half8v bo0, bo1, bo2, bo3, bo4, bo5, bo6, bo7;

#define LOADA(K0, d0a, d0b, d1a, d1b)         \
  do {                                        \
    d0a = *(const f32x4*)(pA0 + (K0));        \
    d0b = *(const f32x4*)(pA0 + (K0) + 4);    \
    d1a = *(const f32x4*)(pA1 + (K0));        \
    d1b = *(const f32x4*)(pA1 + (K0) + 4);    \
  } while (0)

  // edge step k0=480: element 480+ko*8+i valid iff < FIN
#define LOADA_EDGE(d0a, d0b, d1a, d1b)                 \
  do {                                                 \
    _Pragma("unroll")                                  \
    for (int i = 0; i < 4; i++) {                      \
      int kk = 480 + ko * 8 + i;                       \
      d0a[i] = (kk < FIN) ? pA0[480 + i] : 0.f;        \
      d1a[i] = (kk < FIN) ? pA1[480 + i] : 0.f;        \
      d0b[i] = (kk + 4 < FIN) ? pA0[484 + i] : 0.f;    \
      d1b[i] = (kk + 4 < FIN) ? pA1[484 + i] : 0.f;    \
    }                                                  \
  } while (0)

#define LOADB(K0, b0, b1, b2, b3, b4, b5, b6, b7) \
  do {                                            \
    b0 = *(const half8v*)(pB0 + (K0));            \
    b1 = *(const half8v*)(pB1 + (K0));            \
    b2 = *(const half8v*)(pB2 + (K0));            \
    b3 = *(const half8v*)(pB3 + (K0));            \
    b4 = *(const half8v*)(pB4 + (K0));            \
    b5 = *(const half8v*)(pB5 + (K0));            \
    b6 = *(const half8v*)(pB6 + (K0));            \
    b7 = *(const half8v*)(pB7 + (K0));            \
  } while (0)

#define CVT_MFMA(d0a, d0b, d1a, d1b, b0, b1, b2, b3, b4, b5, b6, b7)                   \
  do {                                                                                 \
    half8v f0, f1;                                                                     \
    _Pragma("unroll")                                                                  \
    for (int i = 0; i < 4; i++) {                                                      \
      f0[i] = (_Float16)d0a[i];                                                        \
      f0[i + 4] = (_Float16)d0b[i];                                                    \
      f1[i] = (_Float16)d1a[i];                                                        \
      f1[i + 4] = (_Float16)d1b[i];                                                    \
    }                                                                                  \
    acc[0][0] = __builtin_amdgcn_mfma_f32_16x16x32_f16(f0, b0, acc[0][0], 0, 0, 0);    \
    acc[1][0] = __builtin_amdgcn_mfma_f32_16x16x32_f16(f1, b0, acc[1][0], 0, 0, 0);    \
    acc[0][1] = __builtin_amdgcn_mfma_f32_16x16x32_f16(f0, b1, acc[0][1], 0, 0, 0);    \
    acc[1][1] = __builtin_amdgcn_mfma_f32_16x16x32_f16(f1, b1, acc[1][1], 0, 0, 0);    \
    acc[0][2] = __builtin_amdgcn_mfma_f32_16x16x32_f16(f0, b2, acc[0][2], 0, 0, 0);    \
    acc[1][2] = __builtin_amdgcn_mfma_f32_16x16x32_f16(f1, b2, acc[1][2], 0, 0, 0);    \
    acc[0][3] = __builtin_amdgcn_mfma_f32_16x16x32_f16(f0, b3, acc[0][3], 0, 0, 0);    \
    acc[1][3] = __builtin_amdgcn_mfma_f32_16x16x32_f16(f1, b3, acc[1][3], 0, 0, 0);    \
    acc[0][4] = __builtin_amdgcn_mfma_f32_16x16x32_f16(f0, b4, acc[0][4], 0, 0, 0);    \
    acc[1][4] = __builtin_amdgcn_mfma_f32_16x16x32_f16(f1, b4, acc[1][4], 0, 0, 0);    \
    acc[0][5] = __builtin_amdgcn_mfma_f32_16x16x32_f16(f0, b5, acc[0][5], 0, 0, 0);    \
    acc[1][5] = __builtin_amdgcn_mfma_f32_16x16x32_f16(f1, b5, acc[1][5], 0, 0, 0);    \
    acc[0][6] = __builtin_amdgcn_mfma_f32_16x16x32_f16(f0, b6, acc[0][6], 0, 0, 0);    \
    acc[1][6] = __builtin_amdgcn_mfma_f32_16x16x32_f16(f1, b6, acc[1][6], 0, 0, 0);    \
    acc[0][7] = __builtin_amdgcn_mfma_f32_16x16x32_f16(f0, b7, acc[0][7], 0, 0, 0);    \
    acc[1][7] = __builtin_amdgcn_mfma_f32_16x16x32_f16(f1, b7, acc[1][7], 0, 0, 0);    \
  } while (0)

  // prologue: steps 0 (even) and 1 (odd)
  LOADA(0, e0a, e0b, e1a, e1b);
  LOADB(0, be0, be1, be2, be3, be4, be5, be6, be7);
  LOADA(32, o0a, o0b, o1a, o1b);
  LOADB(32, bo0, bo1, bo2, bo3, bo4, bo5, bo6, bo7);

  // steps 0..11, prefetching steps 2..13
#pragma unroll
  for (int k = 0; k < 12; k += 2) {
    CVT_MFMA(e0a, e0b, e1a, e1b, be0, be1, be2, be3, be4, be5, be6, be7);
    LOADA((k + 2) * 32, e0a, e0b, e1a, e1b);
    LOADB((k + 2) * 32, be0, be1, be2, be3, be4, be5, be6, be7);
    CVT_MFMA(o0a, o0b, o1a, o1b, bo0, bo1, bo2, bo3, bo4, bo5, bo6, bo7);
    LOADA((k + 3) * 32, o0a, o0b, o1a, o1b);
    LOADB((k + 3) * 32, bo0, bo1, bo2, bo3, bo4, bo5, bo6, bo7);
  }
  // step 12 (even), prefetch step 14 -> even
  CVT_MFMA(e0a, e0b, e1a, e1b, be0, be1, be2, be3, be4, be5, be6, be7);
  LOADA(448, e0a, e0b, e1a, e1b);
  LOADB(448, be0, be1, be2, be3, be4, be5, be6, be7);
  // step 13 (odd), prefetch step 15 (edge) -> odd
  CVT_MFMA(o0a, o0b, o1a, o1b, bo0, bo1, bo2, bo3, bo4, bo5, bo6, bo7);
  LOADA_EDGE(o0a, o0b, o1a, o1b);
  LOADB(480, bo0, bo1, bo2, bo3, bo4, bo5, bo6, bo7);
  // steps 14, 15
  CVT_MFMA(e0a, e0b, e1a, e1b, be0, be1, be2, be3, be4, be5, be6, be7);
  CVT_MFMA(o0a, o0b, o1a, o1b, bo0, bo1, bo2, bo3, bo4, bo5, bo6, bo7);

#undef LOADA
#undef LOADA_EDGE
#undef LOADB
#undef CVT_MFMA

  // epilogue: z1h stores + fused el/er (wave owns rows bm..bm+31)
  float alv[8], arv[8];
#pragma unroll
  for (int ni = 0; ni < 8; ni++) {
    alv[ni] = al[ni * 16 + fr];
    arv[ni] = ar[ni * 16 + fr];
  }
#pragma unroll
  for (int mi = 0; mi < 2; mi++) {
#pragma unroll
    for (int r = 0; r < 4; r++) {
      int grow = bm + mi * 16 + ko * 4 + r;
      bool ok = grow < NNODES;
      if (ok) {
#pragma unroll
        for (int ni = 0; ni < 8; ni++)
          z1h[(size_t)grow * HID + ni * 16 + fr] = __float2half(acc[mi][ni][r]);
      }
#pragma unroll
      for (int h = 0; h < 4; h++) {
        float cl = acc[mi][2 * h][r] * alv[2 * h] + acc[mi][2 * h + 1][r] * alv[2 * h + 1];
        float cr = acc[mi][2 * h][r] * arv[2 * h] + acc[mi][2 * h + 1][r] * arv[2 * h + 1];
#pragma unroll
        for (int m = 1; m <= 8; m <<= 1) {
          cl += __shfl_xor(cl, m);
          cr += __shfl_xor(cr, m);
        }
        if (fr == 0 && ok) {
          el[grow * NH + h] = cl;
          er[grow * NH + h] = cr;
        }
      }
    }
  }
}

// ---------------- CSR offsets from sorted dst ----------------
__global__ void csr_offsets_kernel(const int* __restrict__ dst, int E, int* __restrict__ off) {
  int n = blockIdx.x * blockDim.x + threadIdx.x;
  if (n > NNODES) return;
  int lo = 0, hi = E;
  while (lo < hi) {
    int mid = (lo + hi) >> 1;
    if (dst[mid] < n) lo = mid + 1; else hi = mid;
  }
  off[n] = lo;
}

// ---------------- layer-1: wave-per-node online-softmax + fp16 aggregation ----------------
__global__ __launch_bounds__(256) void gat1_agg_kernel(const __half* __restrict__ z1h,
                                                       const float* __restrict__ el,
                                                       const float* __restrict__ er,
                                                       const int* __restrict__ src,
                                                       const int* __restrict__ off,
                                                       const float* __restrict__ b1,
                                                       float* __restrict__ h1) {
  int wid = threadIdx.x >> 6, lane = threadIdx.x & 63;
  int n = blockIdx.x * 4 + wid;
  if (n >= NNODES) return;
  __shared__ float p_sh[4][64 * 4];

  int start = off[n], end = off[n + 1];
  const float4* el4 = reinterpret_cast<const float4*>(el);
  float4 er4 = reinterpret_cast<const float4*>(er)[n];
  const __half2* zp = reinterpret_cast<const __half2*>(z1h);

  int c = lane;
  int head = c >> 4;
  float2 acc = make_float2(0.f, 0.f);
  float m0 = -INFINITY, m1 = -INFINITY, m2 = -INFINITY, m3 = -INFINITY;
  float d0 = 0.f, d1 = 0.f, d2 = 0.f, d3 = 0.f;

  for (int base = start; base < end; base += 64) {
    int cnt = min(64, end - base);
    int sr = 0;
    float e0 = -INFINITY, e1 = -INFINITY, e2 = -INFINITY, e3 = -INFINITY;
    if (lane < cnt) {
      sr = src[base + lane];
      float4 x = el4[sr];
      e0 = lrelu(x.x + er4.x);
      e1 = lrelu(x.y + er4.y);
      e2 = lrelu(x.z + er4.z);
      e3 = lrelu(x.w + er4.w);
    }
    float x0 = e0, x1 = e1, x2 = e2, x3 = e3;
#pragma unroll
    for (int msk = 32; msk >= 1; msk >>= 1) {
      x0 = fmaxf(x0, __shfl_xor(x0, msk));
      x1 = fmaxf(x1, __shfl_xor(x1, msk));
      x2 = fmaxf(x2, __shfl_xor(x2, msk));
      x3 = fmaxf(x3, __shfl_xor(x3, msk));
    }
    float n0 = fmaxf(m0, x0), n1 = fmaxf(m1, x1), n2 = fmaxf(m2, x2), n3 = fmaxf(m3, x3);
    float p0 = 0.f, p1 = 0.f, p2 = 0.f, p3 = 0.f;
    if (lane < cnt) {
      p0 = __expf(e0 - n0); p1 = __expf(e1 - n1);
      p2 = __expf(e2 - n2); p3 = __expf(e3 - n3);
    }
    float s0 = p0, s1 = p1, s2 = p2, s3 = p3;
#pragma unroll
    for (int msk = 32; msk >= 1; msk >>= 1) {
      s0 += __shfl_xor(s0, msk);
      s1 += __shfl_xor(s1, msk);
      s2 += __shfl_xor(s2, msk);
      s3 += __shfl_xor(s3, msk);
    }
    float sc0 = __expf(m0 - n0), sc1 = __expf(m1 - n1);
    float sc2 = __expf(m2 - n2), sc3 = __expf(m3 - n3);
    d0 = d0 * sc0 + s0; d1 = d1 * sc1 + s1;
    d2 = d2 * sc2 + s2; d3 = d3 * sc3 + s3;
    m0 = n0; m1 = n1; m2 = n2; m3 = n3;
    float sch = sel4(sc0, sc1, sc2, sc3, head);
    acc.x *= sch;
    acc.y *= sch;
    *(float4*)&p_sh[wid][lane * 4] = make_float4(p0, p1, p2, p3);
    __builtin_amdgcn_wave_barrier();
    int i = 0;
    for (; i + 1 < cnt; i += 2) {
      int sa = __shfl(sr, i), sb = __shfl(sr, i + 1);
      float pa = p_sh[wid][i * 4 + head];
      float pb = p_sh[wid][(i + 1) * 4 + head];
      float2 va = __half22float2(zp[(size_t)sa * 64 + c]);
      float2 vb = __half22float2(zp[(size_t)sb * 64 + c]);
      acc.x = fmaf(pa, va.x, acc.x); acc.y = fmaf(pa, va.y, acc.y);
      acc.x = fmaf(pb, vb.x, acc.x); acc.y = fmaf(pb, vb.y, acc.y);
    }
    if (i < cnt) {
      int sa = __shfl(sr, i);
      float pa = p_sh[wid][i * 4 + head];
      float2 va = __half22float2(zp[(size_t)sa * 64 + c]);
      acc.x = fmaf(pa, va.x, acc.x); acc.y = fmaf(pa, va.y, acc.y);
    }
    __builtin_amdgcn_wave_barrier();
  }

  float dh = sel4(d0, d1, d2, d3, head);
  float inv = 1.f / fmaxf(dh, 1e-9f);
  float2 bias = reinterpret_cast<const float2*>(b1)[c];
  float v0 = acc.x * inv + bias.x;
  float v1 = acc.y * inv + bias.y;
  v0 = v0 > 0.f ? v0 : __expf(v0) - 1.f;
  v1 = v1 > 0.f ? v1 : __expf(v1) - 1.f;
  reinterpret_cast<float2*>(h1)[(size_t)n * 64 + c] = make_float2(v0, v1);
}

// ---------------- layer-2 projection: wave-per-node ----------------
__global__ __launch_bounds__(256) void proj2_kernel(const float* __restrict__ h1,
                                                    const float* __restrict__ W2,
                                                    const float* __restrict__ al2,
                                                    const float* __restrict__ ar2,
                                                    float4* __restrict__ z2el,
                                                    float* __restrict__ er2) {
  int wid = threadIdx.x >> 6, lane = threadIdx.x & 63;
  int n = blockIdx.x * 4 + wid;
  if (n >= NNODES) return;
  float2 hv = reinterpret_cast<const float2*>(h1)[(size_t)n * 64 + lane];
  int c0 = 2 * lane, c1 = 2 * lane + 1;
  float p0 = hv.x * W2[c0 * 3 + 0] + hv.y * W2[c1 * 3 + 0];
  float p1 = hv.x * W2[c0 * 3 + 1] + hv.y * W2[c1 * 3 + 1];
  float p2 = hv.x * W2[c0 * 3 + 2] + hv.y * W2[c1 * 3 + 2];
#pragma unroll
  for (int msk = 32; msk >= 1; msk >>= 1) {
    p0 += __shfl_xor(p0, msk);
    p1 += __shfl_xor(p1, msk);
    p2 += __shfl_xor(p2, msk);
  }
  if (lane == 0) {
    z2el[n] = make_float4(p0, p1, p2, p0 * al2[0] + p1 * al2[1] + p2 * al2[2]);
    er2[n] = p0 * ar2[0] + p1 * ar2[1] + p2 * ar2[2];
  }
}

// ---------------- layer-2: wave-per-node single-pass softmax + aggregation ----------------
__global__ __launch_bounds__(256) void gat2_agg_kernel(const float4* __restrict__ z2el,
                                                       const float* __restrict__ er2,
                                                       const int* __restrict__ src,
                                                       const int* __restrict__ off,
                                                       const float* __restrict__ b2,
                                                       float* __restrict__ out) {
  int wid = threadIdx.x >> 6, lane = threadIdx.x & 63;
  int n = blockIdx.x * 4 + wid;
  if (n >= NNODES) return;
  int start = off[n], end = off[n + 1];
  float ern = er2[n];
  float m_run = -INFINITY, d_run = 0.f;
  float a0 = 0.f, a1 = 0.f, a2 = 0.f;
  for (int base = start; base < end; base += 64) {
    int cnt = min(64, end - base);
    float4 z4 = make_float4(0.f, 0.f, 0.f, 0.f);
    float e = -INFINITY;
    if (lane < cnt) {
      z4 = z2el[src[base + lane]];
      e = lrelu(z4.w + ern);
    }
    float mx = e;
#pragma unroll
    for (int msk = 32; msk >= 1; msk >>= 1) mx = fmaxf(mx, __shfl_xor(mx, msk));
    float m_new = fmaxf(m_run, mx);
    float p = (lane < cnt) ? __expf(e - m_new) : 0.f;
    float sm = p;
#pragma unroll
    for (int msk = 32; msk >= 1; msk >>= 1) sm += __shfl_xor(sm, msk);
    float scale = __expf(m_run - m_new);
    d_run = d_run * scale + sm;
    a0 = a0 * scale + p * z4.x;
    a1 = a1 * scale + p * z4.y;
    a2 = a2 * scale + p * z4.z;
    m_run = m_new;
  }
#pragma unroll
  for (int msk = 32; msk >= 1; msk >>= 1) {
    a0 += __shfl_xor(a0, msk);
    a1 += __shfl_xor(a1, msk);
    a2 += __shfl_xor(a2, msk);
  }
  if (lane == 0) {
    float inv = 1.f / fmaxf(d_run, 1e-9f);
    out[n * 3 + 0] = a0 * inv + b2[0];
    out[n * 3 + 1] = a1 * inv + b2[1];
    out[n * 3 + 2] = a2 * inv + b2[2];
  }
}

extern "C" void kernel_launch(void* const* d_in, const int* in_sizes, int n_in,
                              void* d_out, int out_size, void* d_ws, size_t ws_size,
                              hipStream_t stream) {
  const float* features = (const float*)d_in[0];
  const int* src = (const int*)d_in[1];
  const int* dst = (const int*)d_in[2];
  const float* W1 = (const float*)d_in[3];
  const float* al1 = (const float*)d_in[4];
  const float* ar1 = (const float*)d_in[5];
  const float* b1 = (const float*)d_in[6];
  const float* W2 = (const float*)d_in[7];
  const float* al2 = (const float*)d_in[8];
  const float* ar2 = (const float*)d_in[9];
  const float* b2 = (const float*)d_in[10];
  float* out = (float*)d_out;
  int E = in_sizes[1];

  char* ws = (char*)d_ws;
  size_t o = 0;
  __half* z1h = (__half*)(ws + o);  o += (size_t)NNODES * HID * 2;
  float* h1 = (float*)(ws + o);     o += (size_t)NNODES * HID * 4;
  float* el1 = (float*)(ws + o);    o += (size_t)NNODES * NH * 4;
  float* er1 = (float*)(ws + o);    o += (size_t)NNODES * NH * 4;
  float4* z2el = (float4*)(ws + o); o += (size_t)NNODES * 16;
  float* er2 = (float*)(ws + o);    o += (size_t)NNODES * 4;
  _Float16* BT = (_Float16*)(ws + o); o += (size_t)HID * KP * 2;
  int* off = (int*)(ws + o);        o += (size_t)(NNODES + 1) * 4;

  convert_w1_kernel<<<256, 256, 0, stream>>>(W1, BT);
  gemm1_mfma_kernel<<<(NNODES + 127) / 128, 256, 0, stream>>>(features, BT, al1, ar1,
                                                              z1h, el1, er1);
  csr_offsets_kernel<<<(NNODES + 1 + 255) / 256, 256, 0, stream>>>(dst, E, off);
  gat1_agg_kernel<<<(NNODES + 3) / 4, 256, 0, stream>>>(z1h, el1, er1, src, off, b1, h1);
  proj2_kernel<<<(NNODES + 3) / 4, 256, 0, stream>>>(h1, W2, al2, ar2, z2el, er2);
  gat2_agg_kernel<<<(NNODES + 3) / 4, 256, 0, stream>>>(z2el, er2, src, off, b2, out);
}

// Round 10
// 253.467 us; speedup vs baseline: 1.1065x; 1.1065x over previous
//
#include <hip/hip_runtime.h>
#include <hip/hip_fp16.h>
#include <math.h>

#define NNODES 100000
#define NEG_SLOPE 0.2f
#define FIN 500
#define KP 512     // padded K
#define HID 128    // heads*hidden
#define NH 4
#define BM 64      // rows per block

typedef __attribute__((ext_vector_type(8))) _Float16 half8v;
typedef __attribute__((ext_vector_type(4))) float f32x4;

__device__ __forceinline__ float lrelu(float x) { return x > 0.f ? x : NEG_SLOPE * x; }

__device__ __forceinline__ float sel4(float a0, float a1, float a2, float a3, int h) {
  float r = a0;
  r = (h == 1) ? a1 : r;
  r = (h == 2) ? a2 : r;
  r = (h == 3) ? a3 : r;
  return r;
}

// swizzled LDS offset (in fp16 elements): row stride 32, 16B slots XOR'd by row
// exact map measured conflict-free (r8: SQ_LDS_BANK_CONFLICT = 0)
__device__ __forceinline__ int lds_off(int row, int slot8) {
  return row * 32 + ((slot8 ^ ((row >> 1) & 3)) << 3);
}

// ---------------- W1 -> transposed fp16 [128][512] (zero-padded K) ----------------
__global__ __launch_bounds__(256) void convert_w1_kernel(const float* __restrict__ W1,
                                                         _Float16* __restrict__ BT) {
  int idx = blockIdx.x * 256 + threadIdx.x;  // 65536
  int n = idx >> 9, k = idx & 511;
  float v = (k < FIN) ? W1[k * HID + n] : 0.f;
  BT[n * KP + k] = (_Float16)v;
}

// ---------------- GEMM1: BM=64, fp16 single-pass, swizzled LDS, fused el/er ----------------
// 4 waves = 2(M) x 2(N); wave tile 32 rows x 64 cols (acc[2][4]); LDS 12 KB; grid 1563.
__global__ __launch_bounds__(256, 4) void gemm1_mfma_kernel(const float* __restrict__ A,
                                                            const _Float16* __restrict__ BT,
                                                            const float* __restrict__ al,
                                                            const float* __restrict__ ar,
                                                            __half* __restrict__ z1h,
                                                            float* __restrict__ el,
                                                            float* __restrict__ er) {
  __shared__ __align__(16) _Float16 AhL[64 * 32];    // 4 KB
  __shared__ __align__(16) _Float16 BhL[128 * 32];   // 8 KB

  const int t = threadIdx.x;
  const int w = t >> 6, lane = t & 63;
  const int wm = w >> 1, wn = w & 1;
  const int fr = lane & 15, ko = lane >> 4;
  const int bm = blockIdx.x * BM;

  // A staging: thread t -> row srow (0..63), slot sslot (8 f32 = 32B)
  const int srow = t >> 2, sslot = t & 3;
  const int arow = min(bm + srow, NNODES - 1);
  const float* pA = A + (size_t)arow * FIN + sslot * 8;
  const int aoff = lds_off(srow, sslot);

  // B staging: thread t -> col=t&127, slots t>>7 and +2 (16B each)
  const int bcol = t & 127, bslot0 = t >> 7, bslot1 = bslot0 + 2;
  const _Float16* pB0 = BT + (size_t)bcol * KP + bslot0 * 8;
  const _Float16* pB1 = BT + (size_t)bcol * KP + bslot1 * 8;
  const int boff0 = lds_off(bcol, bslot0);
  const int boff1 = lds_off(bcol, bslot1);

  f32x4 acc[2][4];
#pragma unroll
  for (int i = 0; i < 2; i++)
#pragma unroll
    for (int j = 0; j < 4; j++) acc[i][j] = (f32x4){0.f, 0.f, 0.f, 0.f};

  // staging registers (1-deep lookahead)
  f32x4 a0, a1;
  half8v sb0, sb1;

#define LOADA_FAST(K0)                       \
  do {                                       \
    a0 = *(const f32x4*)(pA + (K0));         \
    a1 = *(const f32x4*)(pA + (K0) + 4);     \
  } while (0)

#define LOADA_EDGE()                                   \
  do {                                                 \
    _Pragma("unroll")                                  \
    for (int i = 0; i < 4; i++) {                      \
      int kk = 480 + sslot * 8 + i;                    \
      a0[i] = (kk < FIN) ? pA[480 + i] : 0.f;          \
      a1[i] = (kk + 4 < FIN) ? pA[484 + i] : 0.f;      \
    }                                                  \
  } while (0)

#define LOADB(K0)                            \
  do {                                       \
    sb0 = *(const half8v*)(pB0 + (K0));      \
    sb1 = *(const half8v*)(pB1 + (K0));      \
  } while (0)

#define WRITE_STAGE()                        \
  do {                                       \
    half8v hv;                               \
    _Pragma("unroll")                        \
    for (int i = 0; i < 4; i++) {            \
      hv[i] = (_Float16)a0[i];               \
      hv[i + 4] = (_Float16)a1[i];           \
    }                                        \
    *(half8v*)&AhL[aoff] = hv;               \
    *(half8v*)&BhL[boff0] = sb0;             \
    *(half8v*)&BhL[boff1] = sb1;             \
  } while (0)

  const int afr0 = lds_off(wm * 32 + fr, ko);
  const int afr1 = lds_off(wm * 32 + 16 + fr, ko);

  // prologue
  LOADA_FAST(0);
  LOADB(0);

#pragma unroll
  for (int k = 0; k < 16; k++) {
    WRITE_STAGE();
    __syncthreads();
    if (k < 15) {
      if (k + 1 == 15) LOADA_EDGE(); else LOADA_FAST((k + 1) * 32);
      LOADB((k + 1) * 32);
    }
    half8v af0 = *(half8v*)&AhL[afr0];
    half8v af1 = *(half8v*)&AhL[afr1];
#pragma unroll
    for (int ni = 0; ni < 4; ni++) {
      half8v bf = *(half8v*)&BhL[lds_off(wn * 64 + ni * 16 + fr, ko)];
      acc[0][ni] = __builtin_amdgcn_mfma_f32_16x16x32_f16(af0, bf, acc[0][ni], 0, 0, 0);
      acc[1][ni] = __builtin_amdgcn_mfma_f32_16x16x32_f16(af1, bf, acc[1][ni], 0, 0, 0);
    }
    __syncthreads();
  }

#undef LOADA_FAST
#undef LOADA_EDGE
#undef LOADB
#undef WRITE_STAGE

  // epilogue: z1h stores + fused el/er; wave covers cols wn*64..wn*64+63 = heads wn*2, wn*2+1
  float alv[4], arv[4];
#pragma unroll
  for (int ni = 0; ni < 4; ni++) {
    alv[ni] = al[wn * 64 + ni * 16 + fr];
    arv[ni] = ar[wn * 64 + ni * 16 + fr];
  }
#pragma unroll
  for (int mi = 0; mi < 2; mi++) {
#pragma unroll
    for (int r = 0; r < 4; r++) {
      int grow = bm + wm * 32 + mi * 16 + ko * 4 + r;
      bool ok = grow < NNODES;
      if (ok) {
#pragma unroll
        for (int ni = 0; ni < 4; ni++)
          z1h[(size_t)grow * HID + wn * 64 + ni * 16 + fr] = __float2half(acc[mi][ni][r]);
      }
#pragma unroll
      for (int j = 0; j < 2; j++) {
        float cl = acc[mi][2 * j][r] * alv[2 * j] + acc[mi][2 * j + 1][r] * alv[2 * j + 1];
        float cr = acc[mi][2 * j][r] * arv[2 * j] + acc[mi][2 * j + 1][r] * arv[2 * j + 1];
#pragma unroll
        for (int m = 1; m <= 8; m <<= 1) {
          cl += __shfl_xor(cl, m);
          cr += __shfl_xor(cr, m);
        }
        if (fr == 0 && ok) {
          el[grow * NH + wn * 2 + j] = cl;
          er[grow * NH + wn * 2 + j] = cr;
        }
      }
    }
  }
}

// ---------------- CSR offsets from sorted dst ----------------
__global__ void csr_offsets_kernel(const int* __restrict__ dst, int E, int* __restrict__ off) {
  int n = blockIdx.x * blockDim.x + threadIdx.x;
  if (n > NNODES) return;
  int lo = 0, hi = E;
  while (lo < hi) {
    int mid = (lo + hi) >> 1;
    if (dst[mid] < n) lo = mid + 1; else hi = mid;
  }
  off[n] = lo;
}

// ---------------- layer-1: wave-per-node online-softmax + fp16 aggregation ----------------
__global__ __launch_bounds__(256) void gat1_agg_kernel(const __half* __restrict__ z1h,
                                                       const float* __restrict__ el,
                                                       const float* __restrict__ er,
                                                       const int* __restrict__ src,
                                                       const int* __restrict__ off,
                                                       const float* __restrict__ b1,
                                                       float* __restrict__ h1) {
  int wid = threadIdx.x >> 6, lane = threadIdx.x & 63;
  int n = blockIdx.x * 4 + wid;
  if (n >= NNODES) return;
  __shared__ float p_sh[4][64 * 4];

  int start = off[n], end = off[n + 1];
  const float4* el4 = reinterpret_cast<const float4*>(el);
  float4 er4 = reinterpret_cast<const float4*>(er)[n];
  const __half2* zp = reinterpret_cast<const __half2*>(z1h);

  int c = lane;
  int head = c >> 4;
  float2 acc = make_float2(0.f, 0.f);
  float m0 = -INFINITY, m1 = -INFINITY, m2 = -INFINITY, m3 = -INFINITY;
  float d0 = 0.f, d1 = 0.f, d2 = 0.f, d3 = 0.f;

  for (int base = start; base < end; base += 64) {
    int cnt = min(64, end - base);
    int sr = 0;
    float e0 = -INFINITY, e1 = -INFINITY, e2 = -INFINITY, e3 = -INFINITY;
    if (lane < cnt) {
      sr = src[base + lane];
      float4 x = el4[sr];
      e0 = lrelu(x.x + er4.x);
      e1 = lrelu(x.y + er4.y);
      e2 = lrelu(x.z + er4.z);
      e3 = lrelu(x.w + er4.w);
    }
    float x0 = e0, x1 = e1, x2 = e2, x3 = e3;
#pragma unroll
    for (int msk = 32; msk >= 1; msk >>= 1) {
      x0 = fmaxf(x0, __shfl_xor(x0, msk));
      x1 = fmaxf(x1, __shfl_xor(x1, msk));
      x2 = fmaxf(x2, __shfl_xor(x2, msk));
      x3 = fmaxf(x3, __shfl_xor(x3, msk));
    }
    float n0 = fmaxf(m0, x0), n1 = fmaxf(m1, x1), n2 = fmaxf(m2, x2), n3 = fmaxf(m3, x3);
    float p0 = 0.f, p1 = 0.f, p2 = 0.f, p3 = 0.f;
    if (lane < cnt) {
      p0 = __expf(e0 - n0); p1 = __expf(e1 - n1);
      p2 = __expf(e2 - n2); p3 = __expf(e3 - n3);
    }
    float s0 = p0, s1 = p1, s2 = p2, s3 = p3;
#pragma unroll
    for (int msk = 32; msk >= 1; msk >>= 1) {
      s0 += __shfl_xor(s0, msk);
      s1 += __shfl_xor(s1, msk);
      s2 += __shfl_xor(s2, msk);
      s3 += __shfl_xor(s3, msk);
    }
    float sc0 = __expf(m0 - n0), sc1 = __expf(m1 - n1);
    float sc2 = __expf(m2 - n2), sc3 = __expf(m3 - n3);
    d0 = d0 * sc0 + s0; d1 = d1 * sc1 + s1;
    d2 = d2 * sc2 + s2; d3 = d3 * sc3 + s3;
    m0 = n0; m1 = n1; m2 = n2; m3 = n3;
    float sch = sel4(sc0, sc1, sc2, sc3, head);
    acc.x *= sch;
    acc.y *= sch;
    *(float4*)&p_sh[wid][lane * 4] = make_float4(p0, p1, p2, p3);
    __builtin_amdgcn_wave_barrier();
    int i = 0;
    for (; i + 1 < cnt; i += 2) {
      int sa = __shfl(sr, i), sb = __shfl(sr, i + 1);
      float pa = p_sh[wid][i * 4 + head];
      float pb = p_sh[wid][(i + 1) * 4 + head];
      float2 va = __half22float2(zp[(size_t)sa * 64 + c]);
      float2 vb = __half22float2(zp[(size_t)sb * 64 + c]);
      acc.x = fmaf(pa, va.x, acc.x); acc.y = fmaf(pa, va.y, acc.y);
      acc.x = fmaf(pb, vb.x, acc.x); acc.y = fmaf(pb, vb.y, acc.y);
    }
    if (i < cnt) {
      int sa = __shfl(sr, i);
      float pa = p_sh[wid][i * 4 + head];
      float2 va = __half22float2(zp[(size_t)sa * 64 + c]);
      acc.x = fmaf(pa, va.x, acc.x); acc.y = fmaf(pa, va.y, acc.y);
    }
    __builtin_amdgcn_wave_barrier();
  }

  float dh = sel4(d0, d1, d2, d3, head);
  float inv = 1.f / fmaxf(dh, 1e-9f);
  float2 bias = reinterpret_cast<const float2*>(b1)[c];
  float v0 = acc.x * inv + bias.x;
  float v1 = acc.y * inv + bias.y;
  v0 = v0 > 0.f ? v0 : __expf(v0) - 1.f;
  v1 = v1 > 0.f ? v1 : __expf(v1) - 1.f;
  reinterpret_cast<float2*>(h1)[(size_t)n * 64 + c] = make_float2(v0, v1);
}

// ---------------- layer-2 projection: wave-per-node ----------------
__global__ __launch_bounds__(256) void proj2_kernel(const float* __restrict__ h1,
                                                    const float* __restrict__ W2,
                                                    const float* __restrict__ al2,
                                                    const float* __restrict__ ar2,
                                                    float4* __restrict__ z2el,
                                                    float* __restrict__ er2) {
  int wid = threadIdx.x >> 6, lane = threadIdx.x & 63;
  int n = blockIdx.x * 4 + wid;
  if (n >= NNODES) return;
  float2 hv = reinterpret_cast<const float2*>(h1)[(size_t)n * 64 + lane];
  int c0 = 2 * lane, c1 = 2 * lane + 1;
  float p0 = hv.x * W2[c0 * 3 + 0] + hv.y * W2[c1 * 3 + 0];
  float p1 = hv.x * W2[c0 * 3 + 1] + hv.y * W2[c1 * 3 + 1];
  float p2 = hv.x * W2[c0 * 3 + 2] + hv.y * W2[c1 * 3 + 2];
#pragma unroll
  for (int msk = 32; msk >= 1; msk >>= 1) {
    p0 += __shfl_xor(p0, msk);
    p1 += __shfl_xor(p1, msk);
    p2 += __shfl_xor(p2, msk);
  }
  if (lane == 0) {
    z2el[n] = make_float4(p0, p1, p2, p0 * al2[0] + p1 * al2[1] + p2 * al2[2]);
    er2[n] = p0 * ar2[0] + p1 * ar2[1] + p2 * ar2[2];
  }
}

// ---------------- layer-2: wave-per-node single-pass softmax + aggregation ----------------
__global__ __launch_bounds__(256) void gat2_agg_kernel(const float4* __restrict__ z2el,
                                                       const float* __restrict__ er2,
                                                       const int* __restrict__ src,
                                                       const int* __restrict__ off,
                                                       const float* __restrict__ b2,
                                                       float* __restrict__ out) {
  int wid = threadIdx.x >> 6, lane = threadIdx.x & 63;
  int n = blockIdx.x * 4 + wid;
  if (n >= NNODES) return;
  int start = off[n], end = off[n + 1];
  float ern = er2[n];
  float m_run = -INFINITY, d_run = 0.f;
  float a0 = 0.f, a1 = 0.f, a2 = 0.f;
  for (int base = start; base < end; base += 64) {
    int cnt = min(64, end - base);
    float4 z4 = make_float4(0.f, 0.f, 0.f, 0.f);
    float e = -INFINITY;
    if (lane < cnt) {
      z4 = z2el[src[base + lane]];
      e = lrelu(z4.w + ern);
    }
    float mx = e;
#pragma unroll
    for (int msk = 32; msk >= 1; msk >>= 1) mx = fmaxf(mx, __shfl_xor(mx, msk));
    float m_new = fmaxf(m_run, mx);
    float p = (lane < cnt) ? __expf(e - m_new) : 0.f;
    float sm = p;
#pragma unroll
    for (int msk = 32; msk >= 1; msk >>= 1) sm += __shfl_xor(sm, msk);
    float scale = __expf(m_run - m_new);
    d_run = d_run * scale + sm;
    a0 = a0 * scale + p * z4.x;
    a1 = a1 * scale + p * z4.y;
    a2 = a2 * scale + p * z4.z;
    m_run = m_new;
  }
#pragma unroll
  for (int msk = 32; msk >= 1; msk >>= 1) {
    a0 += __shfl_xor(a0, msk);
    a1 += __shfl_xor(a1, msk);
    a2 += __shfl_xor(a2, msk);
  }
  if (lane == 0) {
    float inv = 1.f / fmaxf(d_run, 1e-9f);
    out[n * 3 + 0] = a0 * inv + b2[0];
    out[n * 3 + 1] = a1 * inv + b2[1];
    out[n * 3 + 2] = a2 * inv + b2[2];
  }
}

extern "C" void kernel_launch(void* const* d_in, const int* in_sizes, int n_in,
                              void* d_out, int out_size, void* d_ws, size_t ws_size,
                              hipStream_t stream) {
  const float* features = (const float*)d_in[0];
  const int* src = (const int*)d_in[1];
  const int* dst = (const int*)d_in[2];
  const float* W1 = (const float*)d_in[3];
  const float* al1 = (const float*)d_in[4];
  const float* ar1 = (const float*)d_in[5];
  const float* b1 = (const float*)d_in[6];
  const float* W2 = (const float*)d_in[7];
  const float* al2 = (const float*)d_in[8];
  const float* ar2 = (const float*)d_in[9];
  const float* b2 = (const float*)d_in[10];
  float* out = (float*)d_out;
  int E = in_sizes[1];

  char* ws = (char*)d_ws;
  size_t o = 0;
  __half* z1h = (__half*)(ws + o);  o += (size_t)NNODES * HID * 2;
  float* h1 = (float*)(ws + o);     o += (size_t)NNODES * HID * 4;
  float* el1 = (float*)(ws + o);    o += (size_t)NNODES * NH * 4;
  float* er1 = (float*)(ws + o);    o += (size_t)NNODES * NH * 4;
  float4* z2el = (float4*)(ws + o); o += (size_t)NNODES * 16;
  float* er2 = (float*)(ws + o);    o += (size_t)NNODES * 4;
  _Float16* BT = (_Float16*)(ws + o); o += (size_t)HID * KP * 2;
  int* off = (int*)(ws + o);        o += (size_t)(NNODES + 1) * 4;

  convert_w1_kernel<<<256, 256, 0, stream>>>(W1, BT);
  gemm1_mfma_kernel<<<(NNODES + BM - 1) / BM, 256, 0, stream>>>(features, BT, al1, ar1,
                                                                z1h, el1, er1);
  csr_offsets_kernel<<<(NNODES + 1 + 255) / 256, 256, 0, stream>>>(dst, E, off);
  gat1_agg_kernel<<<(NNODES + 3) / 4, 256, 0, stream>>>(z1h, el1, er1, src, off, b1, h1);
  proj2_kernel<<<(NNODES + 3) / 4, 256, 0, stream>>>(h1, W2, al2, ar2, z2el, er2);
  gat2_agg_kernel<<<(NNODES + 3) / 4, 256, 0, stream>>>(z2el, er2, src, off, b2, out);
}

// Round 11
// 241.410 us; speedup vs baseline: 1.1618x; 1.0499x over previous
//
#include <hip/hip_runtime.h>
#include <hip/hip_fp16.h>
#include <math.h>

#define NNODES 100000
#define NEG_SLOPE 0.2f
#define FIN 500
#define KP 512     // padded K
#define HID 128    // heads*hidden
#define NH 4
#define BM 64      // rows per block (4 waves x 16 rows)

typedef __attribute__((ext_vector_type(8))) _Float16 half8v;
typedef __attribute__((ext_vector_type(4))) float f32x4;

__device__ __forceinline__ float lrelu(float x) { return x > 0.f ? x : NEG_SLOPE * x; }

__device__ __forceinline__ float sel4(float a0, float a1, float a2, float a3, int h) {
  float r = a0;
  r = (h == 1) ? a1 : r;
  r = (h == 2) ? a2 : r;
  r = (h == 3) ? a3 : r;
  return r;
}

// ---------------- W1 -> transposed fp16 [128][512] (zero-padded K) ----------------
__global__ __launch_bounds__(256) void convert_w1_kernel(const float* __restrict__ W1,
                                                         _Float16* __restrict__ BT) {
  int idx = blockIdx.x * 256 + threadIdx.x;  // 65536
  int n = idx >> 9, k = idx & 511;
  float v = (k < FIN) ? W1[k * HID + n] : 0.f;
  BT[n * KP + k] = (_Float16)v;
}

// ---------------- GEMM1: bulk-load / bulk-compute, 3 barriers total ----------------
// B fp16 staged to LDS in two 64KB K-halves; A bulk-issued to registers (8 steps at a
// time) and drained ONCE per half alongside B staging. Compute regions are pure
// LDS+MFMA. Wave tile 16 rows x 128 cols. Swizzle slot^(col&7): b128-minimum banked.
__global__ __launch_bounds__(256, 2) void gemm1_mfma_kernel(const float* __restrict__ A,
                                                            const _Float16* __restrict__ BT,
                                                            const float* __restrict__ al,
                                                            const float* __restrict__ ar,
                                                            __half* __restrict__ z1h,
                                                            float* __restrict__ el,
                                                            float* __restrict__ er) {
  __shared__ __align__(16) _Float16 Bs[128 * 256];   // 64 KB (one K-half of B)

  const int t = threadIdx.x;
  const int w = t >> 6, lane = t & 63;
  const int fr = lane & 15, ko = lane >> 4;
  const int bm = blockIdx.x * BM;

  const int arow = min(bm + w * 16 + fr, NNODES - 1);
  const float* pA = A + (size_t)arow * FIN;

  // B staging map: thread t -> col=t&127, slot group shs=t>>7 (16 slots of 16B = 256B)
  const int scol = t & 127, shs = t >> 7;
  const _Float16* pBT = BT + (size_t)scol * KP + shs * 128;  // + khalf*256

  f32x4 acc[8];
#pragma unroll
  for (int i = 0; i < 8; i++) acc[i] = (f32x4){0.f, 0.f, 0.f, 0.f};

  // A batch registers: 8 steps x 2 f32x4 (64 VGPR)
  f32x4 rA0, rB0, rA1, rB1, rA2, rB2, rA3, rB3, rA4, rB4, rA5, rB5, rA6, rB6, rA7, rB7;

#define LA(S, RA, RB)                                   \
  do {                                                  \
    RA = *(const f32x4*)(pA + (S) * 32 + ko * 8);       \
    RB = *(const f32x4*)(pA + (S) * 32 + ko * 8 + 4);   \
  } while (0)

  // step 15 edge: k = 480 + ko*8 + i (and +4) valid iff < FIN
#define LAE(RA, RB)                                     \
  do {                                                  \
    _Pragma("unroll")                                   \
    for (int i = 0; i < 4; i++) {                       \
      int k0 = 480 + ko * 8 + i;                        \
      RA[i] = (k0 < FIN) ? pA[k0] : 0.f;                \
      RB[i] = (k0 + 4 < FIN) ? pA[k0 + 4] : 0.f;        \
    }                                                   \
  } while (0)

#define STAGEB(KH)                                                         \
  do {                                                                     \
    _Pragma("unroll")                                                      \
    for (int j = 0; j < 16; j++) {                                         \
      half8v v = *(const half8v*)(pBT + (KH) * 256 + j * 8);               \
      int slot = shs * 16 + j;                                             \
      *(half8v*)&Bs[scol * 256 + ((slot ^ (scol & 7)) << 3)] = v;          \
    }                                                                      \
  } while (0)

  // one k-step: convert f32 pair -> fp16 frag, 8 B ds_reads + 8 MFMA
#define STEP(SL, RA, RB)                                                               \
  do {                                                                                 \
    half8v af;                                                                         \
    _Pragma("unroll")                                                                  \
    for (int i = 0; i < 4; i++) {                                                      \
      af[i] = (_Float16)RA[i];                                                         \
      af[i + 4] = (_Float16)RB[i];                                                     \
    }                                                                                  \
    _Pragma("unroll")                                                                  \
    for (int ni = 0; ni < 8; ni++) {                                                   \
      int col = ni * 16 + fr;                                                          \
      int slot = (SL) * 4 + ko;                                                        \
      half8v bf = *(half8v*)&Bs[col * 256 + ((slot ^ (fr & 7)) << 3)];                 \
      acc[ni] = __builtin_amdgcn_mfma_f32_16x16x32_f16(af, bf, acc[ni], 0, 0, 0);      \
    }                                                                                  \
  } while (0)

  // ---- half 0: bulk-issue A steps 0..7, stage B half 0, ONE drain ----
  LA(0, rA0, rB0); LA(1, rA1, rB1); LA(2, rA2, rB2); LA(3, rA3, rB3);
  LA(4, rA4, rB4); LA(5, rA5, rB5); LA(6, rA6, rB6); LA(7, rA7, rB7);
  STAGEB(0);
  __syncthreads();

  STEP(0, rA0, rB0); STEP(1, rA1, rB1); STEP(2, rA2, rB2); STEP(3, rA3, rB3);
  STEP(4, rA4, rB4); STEP(5, rA5, rB5); STEP(6, rA6, rB6); STEP(7, rA7, rB7);

  __syncthreads();  // all reads of Bs half 0 done

  // ---- half 1: bulk-issue A steps 8..15, stage B half 1, ONE drain ----
  LA(8, rA0, rB0); LA(9, rA1, rB1); LA(10, rA2, rB2); LA(11, rA3, rB3);
  LA(12, rA4, rB4); LA(13, rA5, rB5); LA(14, rA6, rB6); LAE(rA7, rB7);
  STAGEB(1);
  __syncthreads();

  STEP(0, rA0, rB0); STEP(1, rA1, rB1); STEP(2, rA2, rB2); STEP(3, rA3, rB3);
  STEP(4, rA4, rB4); STEP(5, rA5, rB5); STEP(6, rA6, rB6); STEP(7, rA7, rB7);

#undef LA
#undef LAE
#undef STAGEB
#undef STEP

  // ---- epilogue: z1h stores + fused el/er (wave owns 16 rows x all 128 cols) ----
  float alv[8], arv[8];
#pragma unroll
  for (int ni = 0; ni < 8; ni++) {
    alv[ni] = al[ni * 16 + fr];
    arv[ni] = ar[ni * 16 + fr];
  }
#pragma unroll
  for (int r = 0; r < 4; r++) {
    int grow = bm + w * 16 + ko * 4 + r;
    bool ok = grow < NNODES;
    if (ok) {
#pragma unroll
      for (int ni = 0; ni < 8; ni++)
        z1h[(size_t)grow * HID + ni * 16 + fr] = __float2half(acc[ni][r]);
    }
#pragma unroll
    for (int h = 0; h < 4; h++) {
      float cl = acc[2 * h][r] * alv[2 * h] + acc[2 * h + 1][r] * alv[2 * h + 1];
      float cr = acc[2 * h][r] * arv[2 * h] + acc[2 * h + 1][r] * arv[2 * h + 1];
#pragma unroll
      for (int m = 1; m <= 8; m <<= 1) {
        cl += __shfl_xor(cl, m);
        cr += __shfl_xor(cr, m);
      }
      if (fr == 0 && ok) {
        el[grow * NH + h] = cl;
        er[grow * NH + h] = cr;
      }
    }
  }
}

// ---------------- CSR offsets from sorted dst ----------------
__global__ void csr_offsets_kernel(const int* __restrict__ dst, int E, int* __restrict__ off) {
  int n = blockIdx.x * blockDim.x + threadIdx.x;
  if (n > NNODES) return;
  int lo = 0, hi = E;
  while (lo < hi) {
    int mid = (lo + hi) >> 1;
    if (dst[mid] < n) lo = mid + 1; else hi = mid;
  }
  off[n] = lo;
}

// ---------------- layer-1: wave-per-node online-softmax + fp16 aggregation ----------------
__global__ __launch_bounds__(256) void gat1_agg_kernel(const __half* __restrict__ z1h,
                                                       const float* __restrict__ el,
                                                       const float* __restrict__ er,
                                                       const int* __restrict__ src,
                                                       const int* __restrict__ off,
                                                       const float* __restrict__ b1,
                                                       float* __restrict__ h1) {
  int wid = threadIdx.x >> 6, lane = threadIdx.x & 63;
  int n = blockIdx.x * 4 + wid;
  if (n >= NNODES) return;
  __shared__ float p_sh[4][64 * 4];

  int start = off[n], end = off[n + 1];
  const float4* el4 = reinterpret_cast<const float4*>(el);
  float4 er4 = reinterpret_cast<const float4*>(er)[n];
  const __half2* zp = reinterpret_cast<const __half2*>(z1h);

  int c = lane;
  int head = c >> 4;
  float2 acc = make_float2(0.f, 0.f);
  float m0 = -INFINITY, m1 = -INFINITY, m2 = -INFINITY, m3 = -INFINITY;
  float d0 = 0.f, d1 = 0.f, d2 = 0.f, d3 = 0.f;

  for (int base = start; base < end; base += 64) {
    int cnt = min(64, end - base);
    int sr = 0;
    float e0 = -INFINITY, e1 = -INFINITY, e2 = -INFINITY, e3 = -INFINITY;
    if (lane < cnt) {
      sr = src[base + lane];
      float4 x = el4[sr];
      e0 = lrelu(x.x + er4.x);
      e1 = lrelu(x.y + er4.y);
      e2 = lrelu(x.z + er4.z);
      e3 = lrelu(x.w + er4.w);
    }
    float x0 = e0, x1 = e1, x2 = e2, x3 = e3;
#pragma unroll
    for (int msk = 32; msk >= 1; msk >>= 1) {
      x0 = fmaxf(x0, __shfl_xor(x0, msk));
      x1 = fmaxf(x1, __shfl_xor(x1, msk));
      x2 = fmaxf(x2, __shfl_xor(x2, msk));
      x3 = fmaxf(x3, __shfl_xor(x3, msk));
    }
    float n0 = fmaxf(m0, x0), n1 = fmaxf(m1, x1), n2 = fmaxf(m2, x2), n3 = fmaxf(m3, x3);
    float p0 = 0.f, p1 = 0.f, p2 = 0.f, p3 = 0.f;
    if (lane < cnt) {
      p0 = __expf(e0 - n0); p1 = __expf(e1 - n1);
      p2 = __expf(e2 - n2); p3 = __expf(e3 - n3);
    }
    float s0 = p0, s1 = p1, s2 = p2, s3 = p3;
#pragma unroll
    for (int msk = 32; msk >= 1; msk >>= 1) {
      s0 += __shfl_xor(s0, msk);
      s1 += __shfl_xor(s1, msk);
      s2 += __shfl_xor(s2, msk);
      s3 += __shfl_xor(s3, msk);
    }
    float sc0 = __expf(m0 - n0), sc1 = __expf(m1 - n1);
    float sc2 = __expf(m2 - n2), sc3 = __expf(m3 - n3);
    d0 = d0 * sc0 + s0; d1 = d1 * sc1 + s1;
    d2 = d2 * sc2 + s2; d3 = d3 * sc3 + s3;
    m0 = n0; m1 = n1; m2 = n2; m3 = n3;
    float sch = sel4(sc0, sc1, sc2, sc3, head);
    acc.x *= sch;
    acc.y *= sch;
    *(float4*)&p_sh[wid][lane * 4] = make_float4(p0, p1, p2, p3);
    __builtin_amdgcn_wave_barrier();
    int i = 0;
    for (; i + 1 < cnt; i += 2) {
      int sa = __shfl(sr, i), sb = __shfl(sr, i + 1);
      float pa = p_sh[wid][i * 4 + head];
      float pb = p_sh[wid][(i + 1) * 4 + head];
      float2 va = __half22float2(zp[(size_t)sa * 64 + c]);
      float2 vb = __half22float2(zp[(size_t)sb * 64 + c]);
      acc.x = fmaf(pa, va.x, acc.x); acc.y = fmaf(pa, va.y, acc.y);
      acc.x = fmaf(pb, vb.x, acc.x); acc.y = fmaf(pb, vb.y, acc.y);
    }
    if (i < cnt) {
      int sa = __shfl(sr, i);
      float pa = p_sh[wid][i * 4 + head];
      float2 va = __half22float2(zp[(size_t)sa * 64 + c]);
      acc.x = fmaf(pa, va.x, acc.x); acc.y = fmaf(pa, va.y, acc.y);
    }
    __builtin_amdgcn_wave_barrier();
  }

  float dh = sel4(d0, d1, d2, d3, head);
  float inv = 1.f / fmaxf(dh, 1e-9f);
  float2 bias = reinterpret_cast<const float2*>(b1)[c];
  float v0 = acc.x * inv + bias.x;
  float v1 = acc.y * inv + bias.y;
  v0 = v0 > 0.f ? v0 : __expf(v0) - 1.f;
  v1 = v1 > 0.f ? v1 : __expf(v1) - 1.f;
  reinterpret_cast<float2*>(h1)[(size_t)n * 64 + c] = make_float2(v0, v1);
}

// ---------------- layer-2 projection: wave-per-node ----------------
__global__ __launch_bounds__(256) void proj2_kernel(const float* __restrict__ h1,
                                                    const float* __restrict__ W2,
                                                    const float* __restrict__ al2,
                                                    const float* __restrict__ ar2,
                                                    float4* __restrict__ z2el,
                                                    float* __restrict__ er2) {
  int wid = threadIdx.x >> 6, lane = threadIdx.x & 63;
  int n = blockIdx.x * 4 + wid;
  if (n >= NNODES) return;
  float2 hv = reinterpret_cast<const float2*>(h1)[(size_t)n * 64 + lane];
  int c0 = 2 * lane, c1 = 2 * lane + 1;
  float p0 = hv.x * W2[c0 * 3 + 0] + hv.y * W2[c1 * 3 + 0];
  float p1 = hv.x * W2[c0 * 3 + 1] + hv.y * W2[c1 * 3 + 1];
  float p2 = hv.x * W2[c0 * 3 + 2] + hv.y * W2[c1 * 3 + 2];
#pragma unroll
  for (int msk = 32; msk >= 1; msk >>= 1) {
    p0 += __shfl_xor(p0, msk);
    p1 += __shfl_xor(p1, msk);
    p2 += __shfl_xor(p2, msk);
  }
  if (lane == 0) {
    z2el[n] = make_float4(p0, p1, p2, p0 * al2[0] + p1 * al2[1] + p2 * al2[2]);
    er2[n] = p0 * ar2[0] + p1 * ar2[1] + p2 * ar2[2];
  }
}

// ---------------- layer-2: wave-per-node single-pass softmax + aggregation ----------------
__global__ __launch_bounds__(256) void gat2_agg_kernel(const float4* __restrict__ z2el,
                                                       const float* __restrict__ er2,
                                                       const int* __restrict__ src,
                                                       const int* __restrict__ off,
                                                       const float* __restrict__ b2,
                                                       float* __restrict__ out) {
  int wid = threadIdx.x >> 6, lane = threadIdx.x & 63;
  int n = blockIdx.x * 4 + wid;
  if (n >= NNODES) return;
  int start = off[n], end = off[n + 1];
  float ern = er2[n];
  float m_run = -INFINITY, d_run = 0.f;
  float a0 = 0.f, a1 = 0.f, a2 = 0.f;
  for (int base = start; base < end; base += 64) {
    int cnt = min(64, end - base);
    float4 z4 = make_float4(0.f, 0.f, 0.f, 0.f);
    float e = -INFINITY;
    if (lane < cnt) {
      z4 = z2el[src[base + lane]];
      e = lrelu(z4.w + ern);
    }
    float mx = e;
#pragma unroll
    for (int msk = 32; msk >= 1; msk >>= 1) mx = fmaxf(mx, __shfl_xor(mx, msk));
    float m_new = fmaxf(m_run, mx);
    float p = (lane < cnt) ? __expf(e - m_new) : 0.f;
    float sm = p;
#pragma unroll
    for (int msk = 32; msk >= 1; msk >>= 1) sm += __shfl_xor(sm, msk);
    float scale = __expf(m_run - m_new);
    d_run = d_run * scale + sm;
    a0 = a0 * scale + p * z4.x;
    a1 = a1 * scale + p * z4.y;
    a2 = a2 * scale + p * z4.z;
    m_run = m_new;
  }
#pragma unroll
  for (int msk = 32; msk >= 1; msk >>= 1) {
    a0 += __shfl_xor(a0, msk);
    a1 += __shfl_xor(a1, msk);
    a2 += __shfl_xor(a2, msk);
  }
  if (lane == 0) {
    float inv = 1.f / fmaxf(d_run, 1e-9f);
    out[n * 3 + 0] = a0 * inv + b2[0];
    out[n * 3 + 1] = a1 * inv + b2[1];
    out[n * 3 + 2] = a2 * inv + b2[2];
  }
}

extern "C" void kernel_launch(void* const* d_in, const int* in_sizes, int n_in,
                              void* d_out, int out_size, void* d_ws, size_t ws_size,
                              hipStream_t stream) {
  const float* features = (const float*)d_in[0];
  const int* src = (const int*)d_in[1];
  const int* dst = (const int*)d_in[2];
  const float* W1 = (const float*)d_in[3];
  const float* al1 = (const float*)d_in[4];
  const float* ar1 = (const float*)d_in[5];
  const float* b1 = (const float*)d_in[6];
  const float* W2 = (const float*)d_in[7];
  const float* al2 = (const float*)d_in[8];
  const float* ar2 = (const float*)d_in[9];
  const float* b2 = (const float*)d_in[10];
  float* out = (float*)d_out;
  int E = in_sizes[1];

  char* ws = (char*)d_ws;
  size_t o = 0;
  __half* z1h = (__half*)(ws + o);  o += (size_t)NNODES * HID * 2;
  float* h1 = (float*)(ws + o);     o += (size_t)NNODES * HID * 4;
  float* el1 = (float*)(ws + o);    o += (size_t)NNODES * NH * 4;
  float* er1 = (float*)(ws + o);    o += (size_t)NNODES * NH * 4;
  float4* z2el = (float4*)(ws + o); o += (size_t)NNODES * 16;
  float* er2 = (float*)(ws + o);    o += (size_t)NNODES * 4;
  _Float16* BT = (_Float16*)(ws + o); o += (size_t)HID * KP * 2;
  int* off = (int*)(ws + o);        o += (size_t)(NNODES + 1) * 4;

  convert_w1_kernel<<<256, 256, 0, stream>>>(W1, BT);
  gemm1_mfma_kernel<<<(NNODES + BM - 1) / BM, 256, 0, stream>>>(features, BT, al1, ar1,
                                                                z1h, el1, er1);
  csr_offsets_kernel<<<(NNODES + 1 + 255) / 256, 256, 0, stream>>>(dst, E, off);
  gat1_agg_kernel<<<(NNODES + 3) / 4, 256, 0, stream>>>(z1h, el1, er1, src, off, b1, h1);
  proj2_kernel<<<(NNODES + 3) / 4, 256, 0, stream>>>(h1, W2, al2, ar2, z2el, er2);
  gat2_agg_kernel<<<(NNODES + 3) / 4, 256, 0, stream>>>(z2el, er2, src, off, b2, out);
}

// Round 13
// 239.979 us; speedup vs baseline: 1.1687x; 1.0060x over previous
//
#include <hip/hip_runtime.h>
#include <hip/hip_fp16.h>
#include <math.h>

#define NNODES 100000
#define NEG_SLOPE 0.2f
#define FIN 500
#define KP 512     // padded K
#define HID 128    // heads*hidden
#define NH 4
#define BM 64      // rows per block (4 waves x 16 rows)

typedef __attribute__((ext_vector_type(8))) _Float16 half8v;
typedef __attribute__((ext_vector_type(4))) float f32x4;

__device__ __forceinline__ float lrelu(float x) { return x > 0.f ? x : NEG_SLOPE * x; }

__device__ __forceinline__ float sel4(float a0, float a1, float a2, float a3, int h) {
  float r = a0;
  r = (h == 1) ? a1 : r;
  r = (h == 2) ? a2 : r;
  r = (h == 3) ? a3 : r;
  return r;
}

// r8-proven conflict-free tile layout (measured SQ_LDS_BANK_CONFLICT = 0):
// within one 8KB k-step tile: col stride 32 shorts (64B), 16B slot XOR'd by (col>>1)&3
__device__ __forceinline__ int tile_off(int col, int slot) {
  return col * 32 + ((slot ^ ((col >> 1) & 3)) << 3);
}

// ---------------- W1 -> transposed fp16 [128][512] (zero-padded K) ----------------
__global__ __launch_bounds__(256) void convert_w1_kernel(const float* __restrict__ W1,
                                                         _Float16* __restrict__ BT) {
  int idx = blockIdx.x * 256 + threadIdx.x;  // 65536
  int n = idx >> 9, k = idx & 511;
  float v = (k < FIN) ? W1[k * HID + n] : 0.f;
  BT[n * KP + k] = (_Float16)v;
}

// ---------------- GEMM1: bulk-load / bulk-compute, 3 barriers, r8 swizzle ----------------
// B fp16 staged to LDS in two 64KB K-halves (8 tiles of 8KB, one per k-step);
// A bulk-issued to registers (8 steps) and drained ONCE per half with B staging.
// Compute regions are pure LDS+MFMA. Wave tile 16 rows x 128 cols.
__global__ __launch_bounds__(256, 2) void gemm1_mfma_kernel(const float* __restrict__ A,
                                                            const _Float16* __restrict__ BT,
                                                            const float* __restrict__ al,
                                                            const float* __restrict__ ar,
                                                            __half* __restrict__ z1h,
                                                            float* __restrict__ el,
                                                            float* __restrict__ er) {
  __shared__ __align__(16) _Float16 Bs[8 * 128 * 32];   // 64 KB = 8 k-step tiles

  const int t = threadIdx.x;
  const int w = t >> 6, lane = t & 63;
  const int fr = lane & 15, ko = lane >> 4;
  const int bm = blockIdx.x * BM;

  const int arow = min(bm + w * 16 + fr, NNODES - 1);
  const float* pA = A + (size_t)arow * FIN;

  // B staging map: thread t -> col=t&127, half-of-K-half shs=t>>7; 16 chunks of 16B
  const int scol = t & 127, shs = t >> 7;
  const _Float16* pBT = BT + (size_t)scol * KP + shs * 128;  // + khalf*256

  f32x4 acc[8];
#pragma unroll
  for (int i = 0; i < 8; i++) acc[i] = (f32x4){0.f, 0.f, 0.f, 0.f};

  // A batch registers: 8 steps x 2 f32x4 (64 VGPR)
  f32x4 rA0, rB0, rA1, rB1, rA2, rB2, rA3, rB3, rA4, rB4, rA5, rB5, rA6, rB6, rA7, rB7;

#define LA(S, RA, RB)                                   \
  do {                                                  \
    RA = *(const f32x4*)(pA + (S) * 32 + ko * 8);       \
    RB = *(const f32x4*)(pA + (S) * 32 + ko * 8 + 4);   \
  } while (0)

  // step 15 edge: k = 480 + ko*8 + i (and +4) valid iff < FIN
#define LAE(RA, RB)                                     \
  do {                                                  \
    _Pragma("unroll")                                   \
    for (int i = 0; i < 4; i++) {                       \
      int k0 = 480 + ko * 8 + i;                        \
      RA[i] = (k0 < FIN) ? pA[k0] : 0.f;                \
      RB[i] = (k0 + 4 < FIN) ? pA[k0 + 4] : 0.f;        \
    }                                                   \
  } while (0)

  // stage one K-half of B: 16 chunks of 16B per thread.
  // Read k-offset within K-half = shs*128 + j*8 (pBT already includes shs*128!);
  // LDS placement slot index idx = shs*16 + j -> tile idx>>2, slot idx&3.
#define STAGEB(KH)                                                         \
  do {                                                                     \
    _Pragma("unroll")                                                      \
    for (int j = 0; j < 16; j++) {                                         \
      int idx = shs * 16 + j;                                              \
      half8v v = *(const half8v*)(pBT + (KH) * 256 + j * 8);               \
      *(half8v*)&Bs[(idx >> 2) * 4096 + tile_off(scol, idx & 3)] = v;      \
    }                                                                      \
  } while (0)

  // one k-step: convert f32 pair -> fp16 frag, 8 B ds_reads + 8 MFMA
#define STEP(SL, RA, RB)                                                               \
  do {                                                                                 \
    half8v af;                                                                         \
    _Pragma("unroll")                                                                  \
    for (int i = 0; i < 4; i++) {                                                      \
      af[i] = (_Float16)RA[i];                                                         \
      af[i + 4] = (_Float16)RB[i];                                                     \
    }                                                                                  \
    _Pragma("unroll")                                                                  \
    for (int ni = 0; ni < 8; ni++) {                                                   \
      half8v bf = *(half8v*)&Bs[(SL) * 4096 + tile_off(ni * 16 + fr, ko)];             \
      acc[ni] = __builtin_amdgcn_mfma_f32_16x16x32_f16(af, bf, acc[ni], 0, 0, 0);      \
    }                                                                                  \
  } while (0)

  // ---- half 0: bulk-issue A steps 0..7, stage B half 0, ONE drain ----
  LA(0, rA0, rB0); LA(1, rA1, rB1); LA(2, rA2, rB2); LA(3, rA3, rB3);
  LA(4, rA4, rB4); LA(5, rA5, rB5); LA(6, rA6, rB6); LA(7, rA7, rB7);
  STAGEB(0);
  __syncthreads();

  STEP(0, rA0, rB0); STEP(1, rA1, rB1); STEP(2, rA2, rB2); STEP(3, rA3, rB3);
  STEP(4, rA4, rB4); STEP(5, rA5, rB5); STEP(6, rA6, rB6); STEP(7, rA7, rB7);

  __syncthreads();  // all reads of Bs half 0 done

  // ---- half 1: bulk-issue A steps 8..15, stage B half 1, ONE drain ----
  LA(8, rA0, rB0); LA(9, rA1, rB1); LA(10, rA2, rB2); LA(11, rA3, rB3);
  LA(12, rA4, rB4); LA(13, rA5, rB5); LA(14, rA6, rB6); LAE(rA7, rB7);
  STAGEB(1);
  __syncthreads();

  STEP(0, rA0, rB0); STEP(1, rA1, rB1); STEP(2, rA2, rB2); STEP(3, rA3, rB3);
  STEP(4, rA4, rB4); STEP(5, rA5, rB5); STEP(6, rA6, rB6); STEP(7, rA7, rB7);

#undef LA
#undef LAE
#undef STAGEB
#undef STEP

  // ---- epilogue: z1h stores + fused el/er (wave owns 16 rows x all 128 cols) ----
  float alv[8], arv[8];
#pragma unroll
  for (int ni = 0; ni < 8; ni++) {
    alv[ni] = al[ni * 16 + fr];
    arv[ni] = ar[ni * 16 + fr];
  }
#pragma unroll
  for (int r = 0; r < 4; r++) {
    int grow = bm + w * 16 + ko * 4 + r;
    bool ok = grow < NNODES;
    if (ok) {
#pragma unroll
      for (int ni = 0; ni < 8; ni++)
        z1h[(size_t)grow * HID + ni * 16 + fr] = __float2half(acc[ni][r]);
    }
#pragma unroll
    for (int h = 0; h < 4; h++) {
      float cl = acc[2 * h][r] * alv[2 * h] + acc[2 * h + 1][r] * alv[2 * h + 1];
      float cr = acc[2 * h][r] * arv[2 * h] + acc[2 * h + 1][r] * arv[2 * h + 1];
#pragma unroll
      for (int m = 1; m <= 8; m <<= 1) {
        cl += __shfl_xor(cl, m);
        cr += __shfl_xor(cr, m);
      }
      if (fr == 0 && ok) {
        el[grow * NH + h] = cl;
        er[grow * NH + h] = cr;
      }
    }
  }
}

// ---------------- CSR offsets from sorted dst ----------------
__global__ void csr_offsets_kernel(const int* __restrict__ dst, int E, int* __restrict__ off) {
  int n = blockIdx.x * blockDim.x + threadIdx.x;
  if (n > NNODES) return;
  int lo = 0, hi = E;
  while (lo < hi) {
    int mid = (lo + hi) >> 1;
    if (dst[mid] < n) lo = mid + 1; else hi = mid;
  }
  off[n] = lo;
}

// ---------------- layer-1: wave-per-node online-softmax + fp16 aggregation ----------------
__global__ __launch_bounds__(256) void gat1_agg_kernel(const __half* __restrict__ z1h,
                                                       const float* __restrict__ el,
                                                       const float* __restrict__ er,
                                                       const int* __restrict__ src,
                                                       const int* __restrict__ off,
                                                       const float* __restrict__ b1,
                                                       float* __restrict__ h1) {
  int wid = threadIdx.x >> 6, lane = threadIdx.x & 63;
  int n = blockIdx.x * 4 + wid;
  if (n >= NNODES) return;
  __shared__ float p_sh[4][64 * 4];

  int start = off[n], end = off[n + 1];
  const float4* el4 = reinterpret_cast<const float4*>(el);
  float4 er4 = reinterpret_cast<const float4*>(er)[n];
  const __half2* zp = reinterpret_cast<const __half2*>(z1h);

  int c = lane;
  int head = c >> 4;
  float2 acc = make_float2(0.f, 0.f);
  float m0 = -INFINITY, m1 = -INFINITY, m2 = -INFINITY, m3 = -INFINITY;
  float d0 = 0.f, d1 = 0.f, d2 = 0.f, d3 = 0.f;

  for (int base = start; base < end; base += 64) {
    int cnt = min(64, end - base);
    int sr = 0;
    float e0 = -INFINITY, e1 = -INFINITY, e2 = -INFINITY, e3 = -INFINITY;
    if (lane < cnt) {
      sr = src[base + lane];
      float4 x = el4[sr];
      e0 = lrelu(x.x + er4.x);
      e1 = lrelu(x.y + er4.y);
      e2 = lrelu(x.z + er4.z);
      e3 = lrelu(x.w + er4.w);
    }
    float x0 = e0, x1 = e1, x2 = e2, x3 = e3;
#pragma unroll
    for (int msk = 32; msk >= 1; msk >>= 1) {
      x0 = fmaxf(x0, __shfl_xor(x0, msk));
      x1 = fmaxf(x1, __shfl_xor(x1, msk));
      x2 = fmaxf(x2, __shfl_xor(x2, msk));
      x3 = fmaxf(x3, __shfl_xor(x3, msk));
    }
    float n0 = fmaxf(m0, x0), n1 = fmaxf(m1, x1), n2 = fmaxf(m2, x2), n3 = fmaxf(m3, x3);
    float p0 = 0.f, p1 = 0.f, p2 = 0.f, p3 = 0.f;
    if (lane < cnt) {
      p0 = __expf(e0 - n0); p1 = __expf(e1 - n1);
      p2 = __expf(e2 - n2); p3 = __expf(e3 - n3);
    }
    float s0 = p0, s1 = p1, s2 = p2, s3 = p3;
#pragma unroll
    for (int msk = 32; msk >= 1; msk >>= 1) {
      s0 += __shfl_xor(s0, msk);
      s1 += __shfl_xor(s1, msk);
      s2 += __shfl_xor(s2, msk);
      s3 += __shfl_xor(s3, msk);
    }
    float sc0 = __expf(m0 - n0), sc1 = __expf(m1 - n1);
    float sc2 = __expf(m2 - n2), sc3 = __expf(m3 - n3);
    d0 = d0 * sc0 + s0; d1 = d1 * sc1 + s1;
    d2 = d2 * sc2 + s2; d3 = d3 * sc3 + s3;
    m0 = n0; m1 = n1; m2 = n2; m3 = n3;
    float sch = sel4(sc0, sc1, sc2, sc3, head);
    acc.x *= sch;
    acc.y *= sch;
    *(float4*)&p_sh[wid][lane * 4] = make_float4(p0, p1, p2, p3);
    __builtin_amdgcn_wave_barrier();
    int i = 0;
    for (; i + 1 < cnt; i += 2) {
      int sa = __shfl(sr, i), sb = __shfl(sr, i + 1);
      float pa = p_sh[wid][i * 4 + head];
      float pb = p_sh[wid][(i + 1) * 4 + head];
      float2 va = __half22float2(zp[(size_t)sa * 64 + c]);
      float2 vb = __half22float2(zp[(size_t)sb * 64 + c]);
      acc.x = fmaf(pa, va.x, acc.x); acc.y = fmaf(pa, va.y, acc.y);
      acc.x = fmaf(pb, vb.x, acc.x); acc.y = fmaf(pb, vb.y, acc.y);
    }
    if (i < cnt) {
      int sa = __shfl(sr, i);
      float pa = p_sh[wid][i * 4 + head];
      float2 va = __half22float2(zp[(size_t)sa * 64 + c]);
      acc.x = fmaf(pa, va.x, acc.x); acc.y = fmaf(pa, va.y, acc.y);
    }
    __builtin_amdgcn_wave_barrier();
  }

  float dh = sel4(d0, d1, d2, d3, head);
  float inv = 1.f / fmaxf(dh, 1e-9f);
  float2 bias = reinterpret_cast<const float2*>(b1)[c];
  float v0 = acc.x * inv + bias.x;
  float v1 = acc.y * inv + bias.y;
  v0 = v0 > 0.f ? v0 : __expf(v0) - 1.f;
  v1 = v1 > 0.f ? v1 : __expf(v1) - 1.f;
  reinterpret_cast<float2*>(h1)[(size_t)n * 64 + c] = make_float2(v0, v1);
}

// ---------------- layer-2 projection: wave-per-node ----------------
__global__ __launch_bounds__(256) void proj2_kernel(const float* __restrict__ h1,
                                                    const float* __restrict__ W2,
                                                    const float* __restrict__ al2,
                                                    const float* __restrict__ ar2,
                                                    float4* __restrict__ z2el,
                                                    float* __restrict__ er2) {
  int wid = threadIdx.x >> 6, lane = threadIdx.x & 63;
  int n = blockIdx.x * 4 + wid;
  if (n >= NNODES) return;
  float2 hv = reinterpret_cast<const float2*>(h1)[(size_t)n * 64 + lane];
  int c0 = 2 * lane, c1 = 2 * lane + 1;
  float p0 = hv.x * W2[c0 * 3 + 0] + hv.y * W2[c1 * 3 + 0];
  float p1 = hv.x * W2[c0 * 3 + 1] + hv.y * W2[c1 * 3 + 1];
  float p2 = hv.x * W2[c0 * 3 + 2] + hv.y * W2[c1 * 3 + 2];
#pragma unroll
  for (int msk = 32; msk >= 1; msk >>= 1) {
    p0 += __shfl_xor(p0, msk);
    p1 += __shfl_xor(p1, msk);
    p2 += __shfl_xor(p2, msk);
  }
  if (lane == 0) {
    z2el[n] = make_float4(p0, p1, p2, p0 * al2[0] + p1 * al2[1] + p2 * al2[2]);
    er2[n] = p0 * ar2[0] + p1 * ar2[1] + p2 * ar2[2];
  }
}

// ---------------- layer-2: wave-per-node single-pass softmax + aggregation ----------------
__global__ __launch_bounds__(256) void gat2_agg_kernel(const float4* __restrict__ z2el,
                                                       const float* __restrict__ er2,
                                                       const int* __restrict__ src,
                                                       const int* __restrict__ off,
                                                       const float* __restrict__ b2,
                                                       float* __restrict__ out) {
  int wid = threadIdx.x >> 6, lane = threadIdx.x & 63;
  int n = blockIdx.x * 4 + wid;
  if (n >= NNODES) return;
  int start = off[n], end = off[n + 1];
  float ern = er2[n];
  float m_run = -INFINITY, d_run = 0.f;
  float a0 = 0.f, a1 = 0.f, a2 = 0.f;
  for (int base = start; base < end; base += 64) {
    int cnt = min(64, end - base);
    float4 z4 = make_float4(0.f, 0.f, 0.f, 0.f);
    float e = -INFINITY;
    if (lane < cnt) {
      z4 = z2el[src[base + lane]];
      e = lrelu(z4.w + ern);
    }
    float mx = e;
#pragma unroll
    for (int msk = 32; msk >= 1; msk >>= 1) mx = fmaxf(mx, __shfl_xor(mx, msk));
    float m_new = fmaxf(m_run, mx);
    float p = (lane < cnt) ? __expf(e - m_new) : 0.f;
    float sm = p;
#pragma unroll
    for (int msk = 32; msk >= 1; msk >>= 1) sm += __shfl_xor(sm, msk);
    float scale = __expf(m_run - m_new);
    d_run = d_run * scale + sm;
    a0 = a0 * scale + p * z4.x;
    a1 = a1 * scale + p * z4.y;
    a2 = a2 * scale + p * z4.z;
    m_run = m_new;
  }
#pragma unroll
  for (int msk = 32; msk >= 1; msk >>= 1) {
    a0 += __shfl_xor(a0, msk);
    a1 += __shfl_xor(a1, msk);
    a2 += __shfl_xor(a2, msk);
  }
  if (lane == 0) {
    float inv = 1.f / fmaxf(d_run, 1e-9f);
    out[n * 3 + 0] = a0 * inv + b2[0];
    out[n * 3 + 1] = a1 * inv + b2[1];
    out[n * 3 + 2] = a2 * inv + b2[2];
  }
}

extern "C" void kernel_launch(void* const* d_in, const int* in_sizes, int n_in,
                              void* d_out, int out_size, void* d_ws, size_t ws_size,
                              hipStream_t stream) {
  const float* features = (const float*)d_in[0];
  const int* src = (const int*)d_in[1];
  const int* dst = (const int*)d_in[2];
  const float* W1 = (const float*)d_in[3];
  const float* al1 = (const float*)d_in[4];
  const float* ar1 = (const float*)d_in[5];
  const float* b1 = (const float*)d_in[6];
  const float* W2 = (const float*)d_in[7];
  const float* al2 = (const float*)d_in[8];
  const float* ar2 = (const float*)d_in[9];
  const float* b2 = (const float*)d_in[10];
  float* out = (float*)d_out;
  int E = in_sizes[1];

  char* ws = (char*)d_ws;
  size_t o = 0;
  __half* z1h = (__half*)(ws + o);  o += (size_t)NNODES * HID * 2;
  float* h1 = (float*)(ws + o);     o += (size_t)NNODES * HID * 4;
  float* el1 = (float*)(ws + o);    o += (size_t)NNODES * NH * 4;
  float* er1 = (float*)(ws + o);    o += (size_t)NNODES * NH * 4;
  float4* z2el = (float4*)(ws + o); o += (size_t)NNODES * 16;
  float* er2 = (float*)(ws + o);    o += (size_t)NNODES * 4;
  _Float16* BT = (_Float16*)(ws + o); o += (size_t)HID * KP * 2;
  int* off = (int*)(ws + o);        o += (size_t)(NNODES + 1) * 4;

  convert_w1_kernel<<<256, 256, 0, stream>>>(W1, BT);
  gemm1_mfma_kernel<<<(NNODES + BM - 1) / BM, 256, 0, stream>>>(features, BT, al1, ar1,
                                                                z1h, el1, er1);
  csr_offsets_kernel<<<(NNODES + 1 + 255) / 256, 256, 0, stream>>>(dst, E, off);
  gat1_agg_kernel<<<(NNODES + 3) / 4, 256, 0, stream>>>(z1h, el1, er1, src, off, b1, h1);
  proj2_kernel<<<(NNODES + 3) / 4, 256, 0, stream>>>(h1, W2, al2, ar2, z2el, er2);
  gat2_agg_kernel<<<(NNODES + 3) / 4, 256, 0, stream>>>(z2el, er2, src, off, b2, out);
}